// Round 1
// baseline (86.442 us; speedup 1.0000x reference)
//
#include <hip/hip_runtime.h>
#include <math.h>

#define N 384
#define DF 128
#define NF4 (DF / 4)
#define TEMP 2.0f
#define SOFT_LAMBDA 0.5f
#define BETA 1.0f
#define EPS_COS 1e-8f
#define EPS_LOG 1e-7f

// ---------------------------------------------------------------------------
// Fused kernel: one block per row i (384 blocks x 512 threads, 8 waves).
// Phase 1: threads 0..383 each own one k, compute pk row {td, rd, eo, lo}
//          directly into LDS (never touches global).
// Phase 2: wave w covers k in [w*48, w*48+48); lane l owns j in
//          {l, l+64, ..., l+320} (stride-64 so dp writes are conflict-free).
//          One wave-uniform broadcast ds_read_b128 per k feeds 12 accumulator
//          chains. Cross-wave denominators reduced through dp[8][N+4].
// Epilogue: per-row pos sums -> partial_h[i], partial_t[i].
// ---------------------------------------------------------------------------
__global__ __launch_bounds__(512, 4) void rnc_fused(
    const float* __restrict__ feat,   // [N, DF]
    const float* __restrict__ rg,     // [N, 3]
    const float* __restrict__ rr,     // [N, 3]
    const float* __restrict__ tr,     // [N, 3]
    const int*   __restrict__ sym,    // [N]
    float* __restrict__ partial_h,    // [N]
    float* __restrict__ partial_t)    // [N]
{
    const int i = blockIdx.x;
    const int t = threadIdx.x;

    __shared__ __align__(16) float4 fi_s[NF4];       // 512 B: feat row i
    __shared__ __align__(16) float4 pks[N];          // 6 KB: {td, rd, eo, lo}
    __shared__ __align__(16) float2 dp[8][N + 4];    // 24.8 KB: [wave][j]
    __shared__ float red_h[8], red_t[8];

    const float4* feat4 = reinterpret_cast<const float4*>(feat);
    if (t < NF4) fi_s[t] = feat4[i * NF4 + t];

    // Row-i labels: blockIdx-uniform addresses -> scalar loads, no LDS needed.
    const float tix = tr[i * 3 + 0], tiy = tr[i * 3 + 1], tiz = tr[i * 3 + 2];
    const float gix = rg[i * 3 + 0], giy = rg[i * 3 + 1], giz = rg[i * 3 + 2];
    const float rix = rr[i * 3 + 0], riy = rr[i * 3 + 1], riz = rr[i * 3 + 2];
    const float ngi = fmaxf(sqrtf(gix * gix + giy * giy + giz * giz), EPS_COS);
    const float nri = fmaxf(sqrtf(rix * rix + riy * riy + riz * riz), EPS_COS);
    const bool symi = (sym[i] == 1);
    __syncthreads();

    // ---- Phase 1: pair table for row i ----
    if (t < N) {
        const int k = t;
        float sq = 0.f;
#pragma unroll 4
        for (int d = 0; d < NF4; ++d) {
            float4 a = fi_s[d];                   // broadcast
            float4 b = feat4[k * NF4 + d];        // L2-resident (feat = 192 KB)
            float dx = a.x - b.x, dy = a.y - b.y, dz = a.z - b.z, dw = a.w - b.w;
            sq += dx * dx + dy * dy + dz * dz + dw * dw;
        }
        float dist = (sq > 0.f) ? sqrtf(sq) : 0.f;
        float lo = -dist * (1.0f / TEMP);         // row max of logits is 0 (diag)
        float eo = (k == i) ? 0.f : expf(lo);     // diag excluded from denominators

        // smooth-L1 trans diff, mean over 3 coords
        float d0 = tix - tr[k * 3 + 0];
        float d1 = tiy - tr[k * 3 + 1];
        float d2 = tiz - tr[k * 3 + 2];
        float a0 = fabsf(d0), a1 = fabsf(d1), a2 = fabsf(d2);
        float s = 0.f;
        s += (a0 < BETA) ? (0.5f * d0 * d0 / BETA) : (a0 - 0.5f * BETA);
        s += (a1 < BETA) ? (0.5f * d1 * d1 / BETA) : (a1 - 0.5f * BETA);
        s += (a2 < BETA) ? (0.5f * d2 * d2 / BETA) : (a2 - 0.5f * BETA);
        float td = s * (1.0f / 3.0f);

        // rot diffs (1 - cosine), eps-clamped norms
        float gkx = rg[k * 3 + 0], gky = rg[k * 3 + 1], gkz = rg[k * 3 + 2];
        float ngk = fmaxf(sqrtf(gkx * gkx + gky * gky + gkz * gkz), EPS_COS);
        float gd = 1.0f - (gix * gkx + giy * gky + giz * gkz) / (ngi * ngk);
        float rkx = rr[k * 3 + 0], rky = rr[k * 3 + 1], rkz = rr[k * 3 + 2];
        float nrk = fmaxf(sqrtf(rkx * rkx + rky * rky + rkz * rkz), EPS_COS);
        float rdif = 1.0f - (rix * rkx + riy * rky + riz * rkz) / (nri * nrk);
        bool ps = symi || (sym[k] == 1);
        float rd = ps ? gd : (gd + rdif);

        pks[k] = make_float4(td, rd, eo, lo);
    }
    __syncthreads();

    // ---- Phase 2: rank denominators ----
    const int w = t >> 6, l = t & 63;
    float tdj[6], rdj[6], dent[6], denh[6];
#pragma unroll
    for (int jj = 0; jj < 6; ++jj) {
        float4 p = pks[l + 64 * jj];
        tdj[jj] = p.x;
        rdj[jj] = p.y;
        dent[jj] = 0.f;
        denh[jj] = 0.f;
    }
    const int k0 = w * 48;
#pragma unroll 4
    for (int k = k0; k < k0 + 48; ++k) {
        float4 p = pks[k];  // wave-uniform -> broadcast
#pragma unroll
        for (int jj = 0; jj < 6; ++jj) {
            bool mt = p.x >= tdj[jj];
            bool mh = mt && (p.y >= rdj[jj]);
            dent[jj] += mt ? p.z : 0.f;
            denh[jj] += mh ? p.z : 0.f;
        }
    }
#pragma unroll
    for (int jj = 0; jj < 6; ++jj)
        dp[w][l + 64 * jj] = make_float2(dent[jj], denh[jj]);
    __syncthreads();

    // ---- Epilogue: per-j pos terms, block reduce ----
    float pos_h = 0.f, pos_t = 0.f;
    if (t < N && t != i) {
        float st_ = 0.f, sh_ = 0.f;
#pragma unroll
        for (int g = 0; g < 8; ++g) {
            float2 v = dp[g][t];
            st_ += v.x;
            sh_ += v.y;
        }
        float lo = pks[t].w;
        pos_h = lo - logf(sh_ + EPS_LOG);
        pos_t = lo - logf(st_ + EPS_LOG);
    }
#pragma unroll
    for (int off = 32; off > 0; off >>= 1) {
        pos_h += __shfl_down(pos_h, off, 64);
        pos_t += __shfl_down(pos_t, off, 64);
    }
    if (l == 0) {
        red_h[w] = pos_h;
        red_t[w] = pos_t;
    }
    __syncthreads();
    if (t == 0) {
        float sh = 0.f, st = 0.f;
#pragma unroll
        for (int g = 0; g < 8; ++g) {
            sh += red_h[g];
            st += red_t[g];
        }
        partial_h[i] = sh;
        partial_t[i] = st;
    }
}

__global__ __launch_bounds__(N) void rnc_final(
    const float* __restrict__ partial_h,
    const float* __restrict__ partial_t,
    float* __restrict__ out)
{
    const int t = threadIdx.x;
    float hsum = partial_h[t];
    float tsum = partial_t[t];
#pragma unroll
    for (int off = 32; off > 0; off >>= 1) {
        hsum += __shfl_down(hsum, off, 64);
        tsum += __shfl_down(tsum, off, 64);
    }
    __shared__ float rh[6], rt[6];
    const int wave = t >> 6, lane = t & 63;
    if (lane == 0) {
        rh[wave] = hsum;
        rt[wave] = tsum;
    }
    __syncthreads();
    if (t == 0) {
        double sh = 0.0, st = 0.0;
#pragma unroll
        for (int w = 0; w < 6; ++w) {
            sh += (double)rh[w];
            st += (double)rt[w];
        }
        const double denom = (double)N * (double)(N - 1);
        out[0] = (float)(-(sh + (double)SOFT_LAMBDA * st) / denom);
    }
}

extern "C" void kernel_launch(void* const* d_in, const int* in_sizes, int n_in,
                              void* d_out, int out_size, void* d_ws, size_t ws_size,
                              hipStream_t stream) {
    const float* feat = (const float*)d_in[0];  // [384,128]
    const float* rg   = (const float*)d_in[1];  // [384,3]
    const float* rr   = (const float*)d_in[2];  // [384,3]
    const float* tr   = (const float*)d_in[3];  // [384,3]
    const int*   sym  = (const int*)d_in[4];    // [384,1]
    float* out = (float*)d_out;

    float* partial_h = (float*)d_ws;            // [384]
    float* partial_t = partial_h + N;           // [384]

    rnc_fused<<<N, 512, 0, stream>>>(feat, rg, rr, tr, sym, partial_h, partial_t);
    rnc_final<<<1, N, 0, stream>>>(partial_h, partial_t, out);
}